// Round 10
// baseline (167.228 us; speedup 1.0000x reference)
//
#include <hip/hip_runtime.h>
#include <float.h>
#include <math.h>

// AdvancedLossFunction: total = 1.0*occ + 0.1*smooth + 0.01*sparse + 0.1*cons
// 2 dispatches. 3-NN via branchless packed-key brute force:
//   key(i,j) = float_bits(d2(i,j)) with low 14 mantissa bits replaced by j.
//   Top-4 keys per i via fmin + 3x v_med3_f32; no branches, no self-check
//   (self d2 ~ 0 is always the minimum key; b1..b3 after merge = the 3 NNs).
// R9 lesson: knn is per-pair ISSUE bound, not occupancy bound (28%->48% occ
//   gave zero speedup) -> ITEMS=8 amortizes per-jj overhead over 8 pairs.
// R7: flat > __any-gated. R6: no bulk contended atomics (staggered ticket ok, R4).

constexpr int   N_ = 16384;
constexpr int   F_ = 64;
constexpr float OCC_W = 1.0f, SMOOTH_W = 0.1f, SPARSE_W = 0.01f, CONS_W = 0.1f;
constexpr float EPS_ = 1e-7f;

// ws layout:
//   0      : float4 part[1024]      (occ, cons, sparse, smooth per merge-block)
//   16384  : unsigned done          (ticket; memset to 0 per call)
//   16640  : float4 cand[CHUNKS][N] (top-4 packed keys per (chunk, i))

__device__ __forceinline__ void ins4f(float t, float& b0, float& b1, float& b2, float& b3) {
  // maintains b0<=b1<=b2<=b3; med3(a,b,t) with a<=b == clamp(t,a,b) == sorted insert
  float n0 = fminf(b0, t);
  float n1 = __builtin_amdgcn_fmed3f(b0, b1, t);
  float n2 = __builtin_amdgcn_fmed3f(b1, b2, t);
  float n3 = __builtin_amdgcn_fmed3f(b2, b3, t);
  b0 = n0; b1 = n1; b2 = n2; b3 = n3;
}

template <int CHUNKS>
__global__ __launch_bounds__(256) void knn_kernel(const float* __restrict__ pts,
                                                  float4* __restrict__ cand) {
  constexpr int CHUNK   = N_ / CHUNKS;             // 128 at CHUNKS=128
  constexpr int TILE    = CHUNK;
  constexpr int ITEMS   = 8;                       // 8 pairs per jj per thread
  constexpr int IPG     = ITEMS * 256;             // 2048 i's per block
  constexpr int IGROUPS = N_ / IPG;                // 8
  int igrp  = blockIdx.x % IGROUPS;
  int chunk = blockIdx.x / IGROUPS;
  int j0    = chunk * CHUNK;

  __shared__ float4 tile[TILE];                    // (-2x,-2y,-2z,|q|^2)

  for (int t = threadIdx.x; t < TILE; t += 256) {
    int j = j0 + t;
    float x = pts[3 * j], y = pts[3 * j + 1], z = pts[3 * j + 2];
    tile[t] = make_float4(-2.f * x, -2.f * y, -2.f * z, fmaf(x, x, fmaf(y, y, z * z)));
  }

  float xi[ITEMS], yi[ITEMS], zi[ITEMS], sqi[ITEMS];
  float b0[ITEMS], b1[ITEMS], b2[ITEMS], b3[ITEMS];
#pragma unroll
  for (int k = 0; k < ITEMS; ++k) {
    int i = igrp * IPG + threadIdx.x + k * 256;
    float x = pts[3 * i], y = pts[3 * i + 1], z = pts[3 * i + 2];
    xi[k] = x; yi[k] = y; zi[k] = z;
    sqi[k] = fmaf(x, x, fmaf(y, y, z * z));
    b0[k] = b1[k] = b2[k] = b3[k] = FLT_MAX;
  }
  __syncthreads();

#pragma unroll 2
  for (int jj = 0; jj < TILE; ++jj) {
    float4 q = tile[jj];                           // wave-uniform -> LDS broadcast
    unsigned jg = (unsigned)(j0 + jj);             // wave-uniform (SGPR) payload
#pragma unroll
    for (int k = 0; k < ITEMS; ++k) {
      float t  = fmaf(xi[k], q.x, fmaf(yi[k], q.y, fmaf(zi[k], q.z, q.w)));  // -2p.q+|q|^2
      float d2 = t + sqi[k];                       // = |p-q|^2 (+- ulps; self ~ 0)
      float kf = __uint_as_float((__float_as_uint(d2) & 0xFFFFC000u) | jg);
      ins4f(kf, b0[k], b1[k], b2[k], b3[k]);       // ~10 flat VALU ops/pair total
    }
  }

#pragma unroll
  for (int k = 0; k < ITEMS; ++k) {
    int i = igrp * IPG + threadIdx.x + k * 256;
    cand[(size_t)chunk * N_ + i] = make_float4(b0[k], b1[k], b2[k], b3[k]);
  }
}

// grid 1024: merge per-chunk top-4s + exact pred gathers -> smoothness, plus all
// scalar reductions (feat float4s covered exactly once). Ticket: last block finalizes.
template <int CHUNKS>
__global__ __launch_bounds__(256) void merge_finalize_kernel(const float* __restrict__ pred,
                                                             const float* __restrict__ targ,
                                                             const float* __restrict__ feat,
                                                             const float4* __restrict__ cand,
                                                             float4* __restrict__ part,
                                                             unsigned* __restrict__ done,
                                                             float* __restrict__ out) {
  __shared__ float4 sh[256];
  __shared__ float ws4[4][4];
  __shared__ int is_last;
  int tid = threadIdx.x;
  int i_local = tid & 15, sub = tid >> 4;          // 16 i's/block, 16 threads/i
  int i = blockIdx.x * 16 + i_local;

  float4 v = ((const float4*)feat)[blockIdx.x * 256 + tid];
  float s_sp = fabsf(v.x) + fabsf(v.y) + fabsf(v.z) + fabsf(v.w);

  constexpr int CPT = CHUNKS / 16;
  float b0 = FLT_MAX, b1 = FLT_MAX, b2 = FLT_MAX, b3 = FLT_MAX;
  for (int cc = 0; cc < CPT; ++cc) {
    float4 q = cand[(size_t)(sub * CPT + cc) * N_ + i];   // 16 consecutive i -> 256B
    ins4f(q.x, b0, b1, b2, b3);
    ins4f(q.y, b0, b1, b2, b3);
    ins4f(q.z, b0, b1, b2, b3);
    ins4f(q.w, b0, b1, b2, b3);
  }
  sh[tid] = make_float4(b0, b1, b2, b3);
  __syncthreads();
  for (int st = 8; st > 0; st >>= 1) {
    if (sub < st) {
      float4 q = sh[((sub + st) << 4) | i_local];
      ins4f(q.x, b0, b1, b2, b3);
      ins4f(q.y, b0, b1, b2, b3);
      ins4f(q.z, b0, b1, b2, b3);
      ins4f(q.w, b0, b1, b2, b3);
      sh[tid] = make_float4(b0, b1, b2, b3);
    }
    __syncthreads();
  }

  float s_occ = 0.f, s_cons = 0.f, s_sm = 0.f;
  if (sub == 0) {                                  // tid < 16: global top-4 for i
    float pi = pred[i], tg = targ[i];
    float p  = fminf(fmaxf(pi, EPS_), 1.0f - EPS_);
    s_occ = -(tg * __logf(p) + (1.0f - tg) * __logf(1.0f - p));
    float d = pi - tg;
    s_cons = d * d;
    // b0 = self (d2~0, minimum); b1..b3 = the 3 NNs; low 14 bits = neighbor index
    float p1 = pred[__float_as_uint(b1) & 0x3FFFu];     // 64KB array: L2-resident gather
    float p2 = pred[__float_as_uint(b2) & 0x3FFFu];
    float p3 = pred[__float_as_uint(b3) & 0x3FFFu];
    s_sm = fabsf(pi - p1) + fabsf(pi - p2) + fabsf(pi - p3);
  }

  for (int off = 32; off > 0; off >>= 1) {         // zeros on lanes >=16 keep sums exact
    s_sp   += __shfl_down(s_sp, off);
    s_occ  += __shfl_down(s_occ, off);
    s_cons += __shfl_down(s_cons, off);
    s_sm   += __shfl_down(s_sm, off);
  }
  if ((tid & 63) == 0) {
    int w = tid >> 6;
    ws4[w][0] = s_occ; ws4[w][1] = s_cons; ws4[w][2] = s_sp; ws4[w][3] = s_sm;
  }
  __syncthreads();
  if (tid == 0) {
    part[blockIdx.x] = make_float4(ws4[0][0] + ws4[1][0] + ws4[2][0] + ws4[3][0],
                                   ws4[0][1] + ws4[1][1] + ws4[2][1] + ws4[3][1],
                                   ws4[0][2] + ws4[1][2] + ws4[2][2] + ws4[3][2],
                                   ws4[0][3] + ws4[1][3] + ws4[2][3] + ws4[3][3]);
    __threadfence();                               // publish part[bid] device-scope
    unsigned prev = atomicAdd(done, 1u);           // staggered: ~free (R4-proven)
    is_last = (prev == (unsigned)(gridDim.x - 1));
  }
  __syncthreads();

  if (is_last) {                                   // one block survives: final sum
    __threadfence();                               // acquire: invalidate stale caches
    float4 a = part[tid], b = part[256 + tid], c = part[512 + tid], d = part[768 + tid];
    float o  = a.x + b.x + c.x + d.x;
    float cn = a.y + b.y + c.y + d.y;
    float sp = a.z + b.z + c.z + d.z;
    float sm = a.w + b.w + c.w + d.w;
    for (int off = 32; off > 0; off >>= 1) {
      o  += __shfl_down(o, off);
      cn += __shfl_down(cn, off);
      sp += __shfl_down(sp, off);
      sm += __shfl_down(sm, off);
    }
    if ((tid & 63) == 0) {
      int w = tid >> 6;
      ws4[w][0] = o; ws4[w][1] = cn; ws4[w][2] = sp; ws4[w][3] = sm;
    }
    __syncthreads();
    if (tid == 0) {
      float occ  = ws4[0][0] + ws4[1][0] + ws4[2][0] + ws4[3][0];
      float cons = ws4[0][1] + ws4[1][1] + ws4[2][1] + ws4[3][1];
      float spar = ws4[0][2] + ws4[1][2] + ws4[2][2] + ws4[3][2];
      float smoo = ws4[0][3] + ws4[1][3] + ws4[2][3] + ws4[3][3];
      out[0] = OCC_W * (occ / (float)N_)
             + CONS_W * (cons / (float)N_)
             + SPARSE_W * (spar / (float)(N_ * F_))
             + SMOOTH_W * (smoo / (float)(N_ * 3));
    }
  }
}

extern "C" void kernel_launch(void* const* d_in, const int* in_sizes, int n_in,
                              void* d_out, int out_size, void* d_ws, size_t ws_size,
                              hipStream_t stream) {
  const float* pred = (const float*)d_in[0];
  const float* targ = (const float*)d_in[1];
  const float* feat = (const float*)d_in[2];
  const float* pts  = (const float*)d_in[3];
  float* out = (float*)d_out;

  char*     ws   = (char*)d_ws;
  float4*   part = (float4*)ws;                    // 16 KB
  unsigned* done = (unsigned*)(ws + 16384);
  float4*   cand = (float4*)(ws + 16640);

  hipMemsetAsync(done, 0, sizeof(unsigned), stream);

  size_t base = 16640;
  auto need = [&](int c) { return base + (size_t)c * N_ * 16; };
  if (ws_size >= need(128)) {
    knn_kernel<128><<<8 * 128, 256, 0, stream>>>(pts, cand);
    merge_finalize_kernel<128><<<1024, 256, 0, stream>>>(pred, targ, feat, cand, part, done, out);
  } else if (ws_size >= need(64)) {
    knn_kernel<64><<<8 * 64, 256, 0, stream>>>(pts, cand);
    merge_finalize_kernel<64><<<1024, 256, 0, stream>>>(pred, targ, feat, cand, part, done, out);
  } else {
    knn_kernel<32><<<8 * 32, 256, 0, stream>>>(pts, cand);
    merge_finalize_kernel<32><<<1024, 256, 0, stream>>>(pred, targ, feat, cand, part, done, out);
  }
}

// Round 11
// 115.378 us; speedup vs baseline: 1.4494x; 1.4494x over previous
//
#include <hip/hip_runtime.h>
#include <float.h>
#include <math.h>

// AdvancedLossFunction: total = 1.0*occ + 0.1*smooth + 0.01*sparse + 0.1*cons
// 2 dispatches. 3-NN via quad-min packed-key brute force:
//   t(i,j) = -2 p_i.q_j + |q_j|^2   (= d2 - |p_i|^2, monotone in d2 per i)
//   knn keeps top-4 of per-QUAD minima: key = bits(min t of 4 j's) & 0xFFFFF000 | quad_id.
//   EXACT coverage: ranked by exact quad-min, self's quad is rank 1 and NNk's quad is
//   rank <= k+1, so the top-4 quads always contain self+NN1..NN3. Merge decodes the
//   4 quads -> 16 candidate j's, re-evaluates exact d2 with index-based self exclusion.
//   21 flat VALU ops per 4 pairs = 5.25/pair (R9/10 measured time ~ ops/pair x ~2.2).
// R10 lessons: ITEMS=8 useless (issue-bound, not occupancy); 1024-block fences +20us.
// R7: flat > branchy. R6: no bulk contended atomics.

constexpr int   N_ = 16384;
constexpr int   F_ = 64;
constexpr float OCC_W = 1.0f, SMOOTH_W = 0.1f, SPARSE_W = 0.01f, CONS_W = 0.1f;
constexpr float EPS_ = 1e-7f;

// ws layout:
//   0    : float4 part[256]       (occ, cons, sparse, smooth per merge-block)
//   4096 : unsigned done          (ticket; zeroed by knn block 0 — no memset dispatch)
//   8192 : float4 cand[CHUNKS][N] (top-4 packed quad keys per (chunk, i))

__device__ __forceinline__ void ins4f(float t, float& b0, float& b1, float& b2, float& b3) {
  // maintains b0<=b1<=b2<=b3; med3(a,b,t) with a<=b == clamp(t,a,b) == sorted insert
  float n0 = fminf(b0, t);
  float n1 = __builtin_amdgcn_fmed3f(b0, b1, t);
  float n2 = __builtin_amdgcn_fmed3f(b1, b2, t);
  float n3 = __builtin_amdgcn_fmed3f(b2, b3, t);
  b0 = n0; b1 = n1; b2 = n2; b3 = n3;
}

template <int CHUNKS>
__global__ __launch_bounds__(256) void knn_kernel(const float* __restrict__ pts,
                                                  float4* __restrict__ cand,
                                                  unsigned* __restrict__ done) {
  constexpr int CHUNK   = N_ / CHUNKS;             // 128 at CHUNKS=128
  constexpr int TILE    = CHUNK;
  constexpr int ITEMS   = 4;
  constexpr int IPG     = 1024;
  constexpr int IGROUPS = N_ / IPG;                // 16
  if (blockIdx.x == 0 && threadIdx.x == 0) *done = 0u;   // ticket init for dispatch 2

  int igrp  = blockIdx.x % IGROUPS;
  int chunk = blockIdx.x / IGROUPS;
  int j0    = chunk * CHUNK;

  __shared__ float4 tile[TILE];                    // (-2x,-2y,-2z,|q|^2)
  for (int t = threadIdx.x; t < TILE; t += 256) {
    int j = j0 + t;
    float x = pts[3 * j], y = pts[3 * j + 1], z = pts[3 * j + 2];
    tile[t] = make_float4(-2.f * x, -2.f * y, -2.f * z, fmaf(x, x, fmaf(y, y, z * z)));
  }

  float xi[ITEMS], yi[ITEMS], zi[ITEMS];
  float b0[ITEMS], b1[ITEMS], b2[ITEMS], b3[ITEMS];
#pragma unroll
  for (int k = 0; k < ITEMS; ++k) {
    int i = igrp * IPG + threadIdx.x + k * 256;
    xi[k] = pts[3 * i]; yi[k] = pts[3 * i + 1]; zi[k] = pts[3 * i + 2];
    b0[k] = b1[k] = b2[k] = b3[k] = FLT_MAX;
  }
  __syncthreads();

  unsigned qbase = (unsigned)(j0 >> 2);            // global quad id base (4096 quads, 12 bits)
#pragma unroll 2
  for (int jq = 0; jq < TILE; jq += 4) {
    float4 qa = tile[jq], qb = tile[jq + 1], qc = tile[jq + 2], qd = tile[jq + 3];
    unsigned qk = qbase + (unsigned)(jq >> 2);
#pragma unroll
    for (int k = 0; k < ITEMS; ++k) {
      float ta = fmaf(xi[k], qa.x, fmaf(yi[k], qa.y, fmaf(zi[k], qa.z, qa.w)));
      float tb = fmaf(xi[k], qb.x, fmaf(yi[k], qb.y, fmaf(zi[k], qb.z, qb.w)));
      float tc = fmaf(xi[k], qc.x, fmaf(yi[k], qc.y, fmaf(zi[k], qc.z, qc.w)));
      float td = fmaf(xi[k], qd.x, fmaf(yi[k], qd.y, fmaf(zi[k], qd.z, qd.w)));
      float tm = fminf(fminf(ta, tb), fminf(tc, td));
      float kf = __uint_as_float((__float_as_uint(tm) & 0xFFFFF000u) | qk);
      ins4f(kf, b0[k], b1[k], b2[k], b3[k]);       // 21 flat ops per 4 pairs
    }
  }

#pragma unroll
  for (int k = 0; k < ITEMS; ++k) {
    int i = igrp * IPG + threadIdx.x + k * 256;
    cand[(size_t)chunk * N_ + i] = make_float4(b0[k], b1[k], b2[k], b3[k]);
  }
}

// grid 256: 64 i's per block, 4 waves each scan CHUNKS/4 chunks; wave 0 merges,
// decodes 4 quads -> 16 candidates, exact d2 + index self-exclusion -> smoothness.
// Plus all scalar reductions. 256-block staggered ticket; last block finalizes.
template <int CHUNKS>
__global__ __launch_bounds__(256) void merge_kernel(const float* __restrict__ pred,
                                                    const float* __restrict__ targ,
                                                    const float* __restrict__ feat,
                                                    const float* __restrict__ pts,
                                                    const float4* __restrict__ cand,
                                                    float4* __restrict__ part,
                                                    unsigned* __restrict__ done,
                                                    float* __restrict__ out) {
  __shared__ float4 sh[256];
  __shared__ float ws4[4][4];
  __shared__ int is_last;
  constexpr int CPT = CHUNKS / 4;
  int tid  = threadIdx.x;
  int lane = tid & 63;                             // i_local
  int sub  = tid >> 6;                             // wave 0..3
  int i = blockIdx.x * 64 + lane;

  // feat: 4 float4 per thread, fully coalesced (covers N*F/4 exactly once)
  const float4* f4 = (const float4*)feat;
  float s_sp = 0.f;
#pragma unroll
  for (int s = 0; s < 4; ++s) {
    float4 v = f4[(size_t)s * 65536 + blockIdx.x * 256 + tid];
    s_sp += fabsf(v.x) + fabsf(v.y) + fabsf(v.z) + fabsf(v.w);
  }

  // per-wave partial merge of this i's chunk keys (wave reads 1KB contiguous per chunk)
  float b0 = FLT_MAX, b1 = FLT_MAX, b2 = FLT_MAX, b3 = FLT_MAX;
#pragma unroll 4
  for (int cc = 0; cc < CPT; ++cc) {
    float4 v = cand[(size_t)(sub * CPT + cc) * N_ + i];
    ins4f(v.x, b0, b1, b2, b3);
    ins4f(v.y, b0, b1, b2, b3);
    ins4f(v.z, b0, b1, b2, b3);
    ins4f(v.w, b0, b1, b2, b3);
  }
  sh[tid] = make_float4(b0, b1, b2, b3);
  __syncthreads();

  float s_occ = 0.f, s_cons = 0.f, s_sm = 0.f;
  if (sub == 0) {                                  // wave 0: final merge + exact re-eval
#pragma unroll
    for (int w = 1; w < 4; ++w) {
      float4 v = sh[w * 64 + lane];
      ins4f(v.x, b0, b1, b2, b3);
      ins4f(v.y, b0, b1, b2, b3);
      ins4f(v.z, b0, b1, b2, b3);
      ins4f(v.w, b0, b1, b2, b3);
    }
    unsigned qs0 = __float_as_uint(b0) & 0xFFFu;
    unsigned qs1 = __float_as_uint(b1) & 0xFFFu;
    unsigned qs2 = __float_as_uint(b2) & 0xFFFu;
    unsigned qs3 = __float_as_uint(b3) & 0xFFFu;
    float xi = pts[3 * i], yi = pts[3 * i + 1], zi = pts[3 * i + 2];
    float c0 = FLT_MAX, c1 = FLT_MAX, c2 = FLT_MAX;
    float p0 = 0.f, p1 = 0.f, p2 = 0.f;
    unsigned qarr[4] = {qs0, qs1, qs2, qs3};       // 4 distinct quads (chunk-partitioned)
#pragma unroll
    for (int s = 0; s < 4; ++s) {
#pragma unroll
      for (int m = 0; m < 4; ++m) {
        int j = (int)(qarr[s] * 4 + m);
        float dx = xi - pts[3 * j], dy = yi - pts[3 * j + 1], dz = zi - pts[3 * j + 2];
        float d2 = fmaf(dx, dx, fmaf(dy, dy, dz * dz));
        float pj = pred[j];
        if (j != i && d2 < c2) {                   // exact top-3, self excluded by index
          bool cc0 = d2 < c0, cc1 = d2 < c1;
          float n2 = cc1 ? c1 : d2;               float m2 = cc1 ? p1 : pj;
          float n1 = cc0 ? c0 : (cc1 ? d2 : c1);  float m1 = cc0 ? p0 : (cc1 ? pj : p1);
          float n0 = cc0 ? d2 : c0;               float m0 = cc0 ? pj : p0;
          c0 = n0; c1 = n1; c2 = n2; p0 = m0; p1 = m1; p2 = m2;
        }
      }
    }
    float pi = pred[i], tg = targ[i];
    float p  = fminf(fmaxf(pi, EPS_), 1.0f - EPS_);
    s_occ  = -(tg * __logf(p) + (1.0f - tg) * __logf(1.0f - p));
    float dd = pi - tg;
    s_cons = dd * dd;
    s_sm   = fabsf(pi - p0) + fabsf(pi - p1) + fabsf(pi - p2);
  }

  // block reduce (lanes with no occ/cons/sm contribute zeros)
  for (int off = 32; off > 0; off >>= 1) {
    s_sp   += __shfl_down(s_sp, off);
    s_occ  += __shfl_down(s_occ, off);
    s_cons += __shfl_down(s_cons, off);
    s_sm   += __shfl_down(s_sm, off);
  }
  if ((tid & 63) == 0) {
    int w = tid >> 6;
    ws4[w][0] = s_occ; ws4[w][1] = s_cons; ws4[w][2] = s_sp; ws4[w][3] = s_sm;
  }
  __syncthreads();
  if (tid == 0) {
    part[blockIdx.x] = make_float4(ws4[0][0] + ws4[1][0] + ws4[2][0] + ws4[3][0],
                                   ws4[0][1] + ws4[1][1] + ws4[2][1] + ws4[3][1],
                                   ws4[0][2] + ws4[1][2] + ws4[2][2] + ws4[3][2],
                                   ws4[0][3] + ws4[1][3] + ws4[2][3] + ws4[3][3]);
    __threadfence();                               // release part[bid]
    unsigned prev = atomicAdd(done, 1u);           // staggered, 256 total
    is_last = (prev == (unsigned)(gridDim.x - 1));
  }
  __syncthreads();

  if (is_last) {                                   // last block: final sum of part[256]
    __threadfence();                               // acquire
    float4 a = part[tid];
    float o = a.x, cn = a.y, sp = a.z, sm = a.w;
    for (int off = 32; off > 0; off >>= 1) {
      o  += __shfl_down(o, off);
      cn += __shfl_down(cn, off);
      sp += __shfl_down(sp, off);
      sm += __shfl_down(sm, off);
    }
    if ((tid & 63) == 0) {
      int w = tid >> 6;
      ws4[w][0] = o; ws4[w][1] = cn; ws4[w][2] = sp; ws4[w][3] = sm;
    }
    __syncthreads();
    if (tid == 0) {
      float occ  = ws4[0][0] + ws4[1][0] + ws4[2][0] + ws4[3][0];
      float cons = ws4[0][1] + ws4[1][1] + ws4[2][1] + ws4[3][1];
      float spar = ws4[0][2] + ws4[1][2] + ws4[2][2] + ws4[3][2];
      float smoo = ws4[0][3] + ws4[1][3] + ws4[2][3] + ws4[3][3];
      out[0] = OCC_W * (occ / (float)N_)
             + CONS_W * (cons / (float)N_)
             + SPARSE_W * (spar / (float)(N_ * F_))
             + SMOOTH_W * (smoo / (float)(N_ * 3));
    }
  }
}

extern "C" void kernel_launch(void* const* d_in, const int* in_sizes, int n_in,
                              void* d_out, int out_size, void* d_ws, size_t ws_size,
                              hipStream_t stream) {
  const float* pred = (const float*)d_in[0];
  const float* targ = (const float*)d_in[1];
  const float* feat = (const float*)d_in[2];
  const float* pts  = (const float*)d_in[3];
  float* out = (float*)d_out;

  char*     ws   = (char*)d_ws;
  float4*   part = (float4*)ws;                    // 4 KB
  unsigned* done = (unsigned*)(ws + 4096);
  float4*   cand = (float4*)(ws + 8192);

  size_t base = 8192;
  auto need = [&](int c) { return base + (size_t)c * N_ * 16; };
  if (ws_size >= need(128)) {
    knn_kernel<128><<<16 * 128, 256, 0, stream>>>(pts, cand, done);
    merge_kernel<128><<<256, 256, 0, stream>>>(pred, targ, feat, pts, cand, part, done, out);
  } else if (ws_size >= need(64)) {
    knn_kernel<64><<<16 * 64, 256, 0, stream>>>(pts, cand, done);
    merge_kernel<64><<<256, 256, 0, stream>>>(pred, targ, feat, pts, cand, part, done, out);
  } else {
    knn_kernel<32><<<16 * 32, 256, 0, stream>>>(pts, cand, done);
    merge_kernel<32><<<256, 256, 0, stream>>>(pred, targ, feat, pts, cand, part, done, out);
  }
}